// Round 1
// baseline (140.472 us; speedup 1.0000x reference)
//
#include <hip/hip_runtime.h>

#define DIM 16
#define NE 120            // edges in the Clements mesh for MODES=16
#define ITEMS 16          // batch items per block
#define THREADS 256
#define USTRIDE 20        // U row stride (floats) -> 80B rows, 16B aligned
#define UITEM 648         // per-item LDS floats: 2*16*20 + 8 pad (== 8 mod 32)
#define LDS_FLOATS (ITEMS * UITEM)   // 10368 floats = 41472 B

__global__ __launch_bounds__(THREADS, 2) void uparam_kernel(
    const float* __restrict__ params,
    const float* __restrict__ state_re,
    const float* __restrict__ state_im,
    float* __restrict__ out)
{
    __shared__ float lds[LDS_FLOATS];

    const int tid  = threadIdx.x;
    const int item = tid >> 4;     // 0..15 within block
    const int r    = tid & 15;     // column during build, row during matmuls
    const long b   = (long)blockIdx.x * ITEMS + item;

    // ---------- Phase A: stage params[16 rows x 240] into LDS, coalesced ----
    {
        const float* src = params + (long)blockIdx.x * ITEMS * (2 * NE);
        #pragma unroll 1
        for (int i = tid; i < ITEMS * 2 * NE; i += THREADS)
            lds[i] = src[i];
    }
    __syncthreads();

    // ---------- Phase B: build U column `r` in registers --------------------
    float Ur[DIM], Ui[DIM];
    #pragma unroll
    for (int i = 0; i < DIM; ++i) { Ur[i] = (i == r) ? 1.0f : 0.0f; Ui[i] = 0.0f; }

    const float* prm = lds + item * (2 * NE);

    #pragma unroll 1
    for (int l2 = 0; l2 < 8; ++l2) {
        const int eb = l2 * 15;   // 8 even-layer + 7 odd-layer edges per pair
        // even layer: pairs (0,1),(2,3)...(14,15)
        #pragma unroll
        for (int j = 0; j < 8; ++j) {
            const int m = 2 * j, n = m + 1;
            const float t = prm[eb + j];
            const float p = prm[NE + eb + j];
            float s, c, sp, cp;
            __sincosf(t, &s, &c);
            __sincosf(p, &sp, &cp);
            const float rmr = Ur[m], rmi = Ui[m], rnr = Ur[n], rni = Ui[n];
            const float ecr = cp * c, eci = sp * c, esr = cp * s, esi = sp * s;
            Ur[m] = ecr * rmr - eci * rmi - s * rnr;
            Ui[m] = ecr * rmi + eci * rmr - s * rni;
            Ur[n] = esr * rmr - esi * rmi + c * rnr;
            Ui[n] = esr * rmi + esi * rmr + c * rni;
        }
        // odd layer: pairs (1,2),(3,4)...(13,14)
        #pragma unroll
        for (int j = 0; j < 7; ++j) {
            const int m = 2 * j + 1, n = m + 1;
            const float t = prm[eb + 8 + j];
            const float p = prm[NE + eb + 8 + j];
            float s, c, sp, cp;
            __sincosf(t, &s, &c);
            __sincosf(p, &sp, &cp);
            const float rmr = Ur[m], rmi = Ui[m], rnr = Ur[n], rni = Ui[n];
            const float ecr = cp * c, eci = sp * c, esr = cp * s, esi = sp * s;
            Ur[m] = ecr * rmr - eci * rmi - s * rnr;
            Ui[m] = ecr * rmi + eci * rmr - s * rni;
            Ur[n] = esr * rmr - esi * rmi + c * rnr;
            Ui[n] = esr * rmi + esi * rmr + c * rni;
        }
    }

    __syncthreads();   // all groups done reading params region

    // ---------- write U (this lane's column) to LDS --------------------------
    float* Ul = lds + item * UITEM;            // Ure[16][20] then Uim[16][20]
    #pragma unroll
    for (int i = 0; i < DIM; ++i) {
        Ul[i * USTRIDE + r] = Ur[i];
        Ul[DIM * USTRIDE + i * USTRIDE + r] = Ui[i];
    }
    __syncthreads();

    // ---------- Phase C: left row r = U[r][:] * rho --------------------------
    float Lr[DIM], Li[DIM];
    #pragma unroll
    for (int k = 0; k < DIM; ++k) { Lr[k] = 0.f; Li[k] = 0.f; }

    const float4* rhor = (const float4*)(state_re + b * (DIM * DIM));
    const float4* rhoi = (const float4*)(state_im + b * (DIM * DIM));
    const float* Urow_r = Ul + r * USTRIDE;
    const float* Urow_i = Ul + DIM * USTRIDE + r * USTRIDE;

    #pragma unroll 1
    for (int j4 = 0; j4 < 4; ++j4) {
        const float4 u4r = *(const float4*)(Urow_r + j4 * 4);
        const float4 u4i = *(const float4*)(Urow_i + j4 * 4);
        const float uar[4] = { u4r.x, u4r.y, u4r.z, u4r.w };
        const float uai[4] = { u4i.x, u4i.y, u4i.z, u4i.w };
        #pragma unroll
        for (int jj = 0; jj < 4; ++jj) {
            const int j = j4 * 4 + jj;
            const float ur = uar[jj], ui = uai[jj];
            #pragma unroll
            for (int k4 = 0; k4 < 4; ++k4) {
                const float4 pr = rhor[j * 4 + k4];
                const float4 pi = rhoi[j * 4 + k4];
                Lr[k4*4+0] += ur * pr.x - ui * pi.x;  Li[k4*4+0] += ur * pi.x + ui * pr.x;
                Lr[k4*4+1] += ur * pr.y - ui * pi.y;  Li[k4*4+1] += ur * pi.y + ui * pr.y;
                Lr[k4*4+2] += ur * pr.z - ui * pi.z;  Li[k4*4+2] += ur * pi.z + ui * pr.z;
                Lr[k4*4+3] += ur * pr.w - ui * pi.w;  Li[k4*4+3] += ur * pi.w + ui * pr.w;
            }
        }
    }

    // ---------- Phase D: out[r][j] = sum_k left[k] * conj(U[j][k]) -----------
    float* outp = out + b * (2 * DIM * DIM) + r * DIM;
    #pragma unroll 1
    for (int jj = 0; jj < 4; ++jj) {
        float orr[4], oii[4];
        #pragma unroll
        for (int j4 = 0; j4 < 4; ++j4) {
            const int j = jj * 4 + j4;
            const float* Uj_r = Ul + j * USTRIDE;
            const float* Uj_i = Ul + DIM * USTRIDE + j * USTRIDE;
            float ar = 0.f, ai = 0.f;
            #pragma unroll
            for (int k4 = 0; k4 < 4; ++k4) {
                const float4 ur4 = *(const float4*)(Uj_r + k4 * 4);
                const float4 ui4 = *(const float4*)(Uj_i + k4 * 4);
                ar += Lr[k4*4+0] * ur4.x + Li[k4*4+0] * ui4.x;
                ai += Li[k4*4+0] * ur4.x - Lr[k4*4+0] * ui4.x;
                ar += Lr[k4*4+1] * ur4.y + Li[k4*4+1] * ui4.y;
                ai += Li[k4*4+1] * ur4.y - Lr[k4*4+1] * ui4.y;
                ar += Lr[k4*4+2] * ur4.z + Li[k4*4+2] * ui4.z;
                ai += Li[k4*4+2] * ur4.z - Lr[k4*4+2] * ui4.z;
                ar += Lr[k4*4+3] * ur4.w + Li[k4*4+3] * ui4.w;
                ai += Li[k4*4+3] * ur4.w - Lr[k4*4+3] * ui4.w;
            }
            orr[j4] = ar; oii[j4] = ai;
        }
        *(float4*)(outp + jj * 4) = make_float4(orr[0], orr[1], orr[2], orr[3]);
        *(float4*)(outp + DIM * DIM + jj * 4) = make_float4(oii[0], oii[1], oii[2], oii[3]);
    }
}

extern "C" void kernel_launch(void* const* d_in, const int* in_sizes, int n_in,
                              void* d_out, int out_size, void* d_ws, size_t ws_size,
                              hipStream_t stream) {
    const float* params   = (const float*)d_in[0];
    const float* state_re = (const float*)d_in[1];
    const float* state_im = (const float*)d_in[2];
    // d_in[3] = targets; structure is the fixed Clements mesh, derived in-kernel.
    float* out = (float*)d_out;

    const int batch = in_sizes[0] / (2 * NE);   // 32768
    dim3 grid(batch / ITEMS);                   // 2048 blocks
    uparam_kernel<<<grid, THREADS, 0, stream>>>(params, state_re, state_im, out);
}